// Round 12
// baseline (476.963 us; speedup 1.0000x reference)
//
#include <hip/hip_runtime.h>
#include <hip/hip_bf16.h>
#include <stdint.h>

// SymmetryAwareBottleneck: conv3x3x3 (x2, implicit GEMM, split-K x4 even 108
// K-tiles/slice, 8-phase 256x256 burst-read counted-vmcnt(6) schedule, 32x32x16
// MFMA) -> GN (stats folded into split-K reduce) -> relu -> merged proj -> 2
// flash attns (QBLK=64, defer-max, double-buffered KV, counted vmcnt(8)) ->
// fused proj (split-K x2, reduce folded into GN) -> GN -> relu ; asym map.

using bf16_t = __bf16;
using bf16x4 = __attribute__((ext_vector_type(4))) __bf16;
using bf16x8 = __attribute__((ext_vector_type(8))) __bf16;
using f32x4  = __attribute__((ext_vector_type(4))) float;
using f32x16 = __attribute__((ext_vector_type(16))) float;

typedef const uint32_t __attribute__((address_space(1)))* gas1_t;
typedef uint32_t __attribute__((address_space(3)))* las3_t;

__device__ __forceinline__ f32x4 mfma16(bf16x8 a, bf16x8 b, f32x4 c) {
  return __builtin_amdgcn_mfma_f32_16x16x32_bf16(a, b, c, 0, 0, 0);
}
__device__ __forceinline__ f32x16 mfma32(bf16x8 a, bf16x8 b, f32x16 c) {
  return __builtin_amdgcn_mfma_f32_32x32x16_bf16(a, b, c, 0, 0, 0);
}
__device__ __forceinline__ void gload_lds16(const void* g, void* l) {
  __builtin_amdgcn_global_load_lds((gas1_t)g, (las3_t)l, 16, 0, 0);
}

// ---------------------------------------------------------------- weight cvt
__global__ __launch_bounds__(256) void convw_kernel(
    const float* __restrict__ wl, const float* __restrict__ wr,
    bf16_t* __restrict__ Wb)
{
  const int chunk = blockIdx.x;            // 0..3  (256 ci each)
  const int co    = blockIdx.y;            // 0..1023
  const int side  = blockIdx.z;
  const float* __restrict__ src = (side ? wr : wl) + (size_t)co * 27648 + (size_t)chunk * 6912;
  __shared__ float L[6912];                // [256 ci][27 t]
  __shared__ bf16_t Lb[27][260];           // [t][ci] bf16 (padded)
  const int tid = threadIdx.x;
  for (int i = tid; i < 1728; i += 256)
    *(float4*)&L[i << 2] = *(const float4*)&src[i << 2];
  __syncthreads();
  {
    const int ci = tid;
#pragma unroll
    for (int t = 0; t < 27; ++t)
      Lb[t][ci] = (bf16_t)L[ci * 27 + t];
  }
  __syncthreads();
  bf16_t* __restrict__ dst = Wb + (size_t)side * (1024u * 27648u) + (size_t)co * 27648 + (chunk << 8);
  for (int u = tid; u < 864; u += 256) {
    const int t = u >> 5, c8 = (u & 31) << 3;
    const bf16x8 v = *(const bf16x8*)&Lb[t][c8];
    *(bf16x8*)&dst[(t << 10) + c8] = v;
  }
}

// proj weights fp32->bf16, stacked: z = ql(QS), kl, kr, qr(QS), vl, vr, fus
__global__ __launch_bounds__(256) void projw_kernel(
    const float* ql, const float* kl, const float* kr, const float* qr,
    const float* vl, const float* vr, const float* fu,
    bf16_t* __restrict__ Wp, float qs)
{
  const int z = blockIdx.y;
  const float* src; float s = 1.f;
  switch (z) {
    case 0: src = ql; s = qs; break;
    case 1: src = kl; break;
    case 2: src = kr; break;
    case 3: src = qr; s = qs; break;
    case 4: src = vl; break;
    case 5: src = vr; break;
    default: src = fu; break;
  }
  const size_t i4 = ((size_t)blockIdx.x * 256 + threadIdx.x) * 4;
  const float4 v = *(const float4*)(src + i4);
  bf16x4 o;
  o[0] = (bf16_t)(v.x * s); o[1] = (bf16_t)(v.y * s);
  o[2] = (bf16_t)(v.z * s); o[3] = (bf16_t)(v.w * s);
  *(bf16x4*)(Wp + (size_t)z * 1048576 + i4) = o;
}

// ------------------------------------------------------------- padded input
__global__ __launch_bounds__(256) void xp_build_kernel(
    const float* __restrict__ x, bf16_t* __restrict__ Xp)
{
  const int cc0  = blockIdx.x << 6;
  const int d    = blockIdx.y;
  const int sb   = blockIdx.z;
  const int side = sb >> 1, b = sb & 1;
  __shared__ bf16_t Tls[64][132];
  const int tid = threadIdx.x;
#pragma unroll
  for (int j = 0; j < 8; ++j) {
    const int u = tid + (j << 8);
    const int ci = u >> 5, sub = u & 31;
    const int hh = sub >> 1, half = sub & 1;
    const float4 v = *(const float4*)&x[((size_t)((b << 10) + cc0 + ci) * 8 + d) * 256 +
                                        (hh << 4) + (side << 3) + (half << 2)];
    bf16x4 o;
    o[0] = (bf16_t)v.x; o[1] = (bf16_t)v.y; o[2] = (bf16_t)v.z; o[3] = (bf16_t)v.w;
    *(bf16x4*)&Tls[ci][(hh << 3) + (half << 2)] = o;
  }
  __syncthreads();
  bf16_t* __restrict__ dst = Xp + (size_t)side * 3686400 + (size_t)b * 1843200;
#pragma unroll
  for (int j = 0; j < 4; ++j) {
    const int u = tid + (j << 8);
    const int hw = u >> 3, c8 = u & 7;
    const int hh = hw >> 3, ww = hw & 7;
    bf16x8 v;
#pragma unroll
    for (int e = 0; e < 8; ++e) v[e] = Tls[(c8 << 3) + e][hw];
    *(bf16x8*)&dst[(size_t)(((d + 1) * 18 + (hh + 1)) * 10 + (ww + 1)) * 1024 + cc0 + (c8 << 3)] = v;
  }
}

// --------------------------------------------------------- conv implicit GEMM
// 8-phase 256x256, BK=64, 8 waves, 128KB LDS dbuf, mfma_32x32x16. Burst LDS
// reads (ph1/2/5/6 only; ph3/4/7/8 pure-register MFMA), counted vmcnt(6) at
// ph4/ph8. Split-K x4 over GLOBAL K-tiles (432 = 27 taps x 16), 108/slice.
#define STAGE_A(BUF, H, TILE)                                                 \
  { const int koff_ = (TILE) << 6;                                            \
    gload_lds16(A + (size_t)arow[H][0] * 27648 + koff_ + swz,                 \
                &Al[BUF][((H) * 128 + (wv << 4)) << 6]);                      \
    gload_lds16(A + (size_t)arow[H][1] * 27648 + koff_ + swz,                 \
                &Al[BUF][(((H) * 128 + (wv << 4)) + 8) << 6]); }

#define STAGE_B(BUF, H, TILE)                                                 \
  { const int t_ = (TILE) >> 4;                                               \
    const int tofs_ = ((t_ / 9) * 18 + ((t_ / 3) % 3)) * 10 + (t_ % 3);       \
    const int cb64_ = ((TILE) & 15) << 6;                                     \
    gload_lds16(X + (size_t)(browbase[H][0] + tofs_) * 1024 + cb64_ + swz,    \
                &Bl[BUF][((H) * 128 + (wv << 4)) << 6]);                      \
    gload_lds16(X + (size_t)(browbase[H][1] + tofs_) * 1024 + cb64_ + swz,    \
                &Bl[BUF][(((H) * 128 + (wv << 4)) + 8) << 6]); }

// B fragments: all 8 (2 n-tiles x 4 k-steps)
#define READ_B32(BUF)                                                         \
  _Pragma("unroll")                                                           \
  for (int tn_ = 0; tn_ < 2; ++tn_)                                           \
    _Pragma("unroll")                                                         \
    for (int ks_ = 0; ks_ < 4; ++ks_) {                                       \
      const int row_ = (wn << 6) + (tn_ << 5) + lane31;                       \
      const int ch_ = ((ks_ << 1) + laneh) ^ (row_ & 7);                      \
      bB[tn_][ks_] = *(const bf16x8*)&Bl[BUF][(row_ << 6) + (ch_ << 3)];      \
    }

// A fragments: m-pair MB (2 m-tiles x 4 k-steps)
#define READ_A32(BUF, MB, DST)                                                \
  _Pragma("unroll")                                                           \
  for (int tm_ = 0; tm_ < 2; ++tm_)                                           \
    _Pragma("unroll")                                                         \
    for (int ks_ = 0; ks_ < 4; ++ks_) {                                       \
      const int row_ = (wm << 7) + (((MB) + tm_) << 5) + lane31;              \
      const int ch_ = ((ks_ << 1) + laneh) ^ (row_ & 7);                      \
      DST[tm_][ks_] = *(const bf16x8*)&Al[BUF][(row_ << 6) + (ch_ << 3)];     \
    }

// 8 mfma_32x32x16: m-pair MB x 2 n-tiles x k-steps {KS0, KS0+1}
#define MFMA8(MB, AF, KS0)                                                    \
  __builtin_amdgcn_s_setprio(1);                                              \
  _Pragma("unroll")                                                           \
  for (int tm_ = 0; tm_ < 2; ++tm_)                                           \
    _Pragma("unroll")                                                         \
    for (int tn_ = 0; tn_ < 2; ++tn_)                                         \
      _Pragma("unroll")                                                       \
      for (int kq_ = 0; kq_ < 2; ++kq_)                                       \
        acc[(MB) + tm_][tn_] = mfma32(AF[tm_][(KS0) + kq_], bB[tn_][(KS0) + kq_], acc[(MB) + tm_][tn_]); \
  __builtin_amdgcn_s_setprio(0);

#define BAR __builtin_amdgcn_s_barrier()
#define LGKM0 asm volatile("s_waitcnt lgkmcnt(0)" ::: "memory")
#define VMC6 asm volatile("s_waitcnt vmcnt(6)" ::: "memory")
#define VMC0 asm volatile("s_waitcnt vmcnt(0)" ::: "memory")

__global__ __launch_bounds__(512, 2) void conv8_kernel(
    const bf16_t* __restrict__ Wb, const bf16_t* __restrict__ Xp,
    bf16_t* __restrict__ Pb)
{
  const int bid = blockIdx.x;
  const int orig = (bid & 7) * 32 + (bid >> 3);   // each XCD owns one (slice,side)
  const int ntile = orig & 7;
  const int mtile = (orig >> 3) & 3;
  const int side  = (orig >> 5) & 1;
  const int slice = orig >> 6;
  const int tb = slice * 108;                     // global K-tile base (432 total)
  const int n0 = ntile << 8;
  const int m0 = mtile << 8;
  const int b = n0 >> 10;

  const bf16_t* __restrict__ A = Wb + (size_t)side * 28311552u;
  const bf16_t* __restrict__ X = Xp + (size_t)side * 3686400 + (size_t)b * 1843200;

  __shared__ bf16_t Al[2][256 * 64];
  __shared__ bf16_t Bl[2][256 * 64];

  const int tid = threadIdx.x;
  const int lane = tid & 63;
  const int wv = tid >> 6;                 // 0..7
  const int wm = wv >> 2, wn = wv & 3;     // 2M x 4N
  const int lane31 = lane & 31, laneh = lane >> 5;
  const int l8 = lane >> 3, l7 = lane & 7;
  const int swz = (l7 ^ l8) << 3;          // pre-swizzled source chunk offset

  int arow[2][2], browbase[2][2];
#pragma unroll
  for (int h = 0; h < 2; ++h)
#pragma unroll
    for (int j = 0; j < 2; ++j) {
      const int r = h * 128 + (wv << 4) + (j << 3) + l8;
      arow[h][j] = m0 + r;
      const int c = n0 + r;
      const int d = (c >> 7) & 7, hh = (c >> 3) & 15, ww = c & 7;
      browbase[h][j] = (d * 18 + hh) * 10 + ww;
    }

  f32x16 acc[4][2];
#pragma unroll
  for (int i = 0; i < 4; ++i)
#pragma unroll
    for (int j = 0; j < 2; ++j)
#pragma unroll
      for (int e = 0; e < 16; ++e) acc[i][j][e] = 0.f;
  bf16x8 bB[2][4], aLo[2][4], aHi[2][4];

  // prologue: buf0 <- tile tb (4 halves), buf1 <- tile tb+1 (Bh0,Bh1,Ah0)
  STAGE_B(0, 0, tb)
  STAGE_B(0, 1, tb)
  STAGE_A(0, 0, tb)
  STAGE_A(0, 1, tb)
  STAGE_B(1, 0, tb + 1)
  STAGE_B(1, 1, tb + 1)
  STAGE_A(1, 0, tb + 1)
  VMC6;                       // oldest 8 loads (buf0) complete
  BAR;

  for (int i = 0; i < 53; ++i) {
    const int tA = tb + 2 * i + 1, tN0 = tb + 2 * i + 2, tN1 = tb + 2 * i + 3;
    // ph1: burst reads (B all + A m-pair0 all-k); stage buf1.Ah1(tA)
    READ_B32(0) READ_A32(0, 0, aLo)
    STAGE_A(1, 1, tA)
    BAR; LGKM0; MFMA8(0, aLo, 0) BAR;
    // ph2: A m-pair2 all-k reads
    READ_A32(0, 2, aHi)
    STAGE_B(0, 0, tN0)
    BAR; LGKM0; MFMA8(2, aHi, 0) BAR;
    // ph3: pure-register
    STAGE_B(0, 1, tN0)
    BAR; MFMA8(0, aLo, 2) BAR;
    // ph4: counted wait -> buf1 (tile tA) complete
    STAGE_A(0, 0, tN0)
    BAR; MFMA8(2, aHi, 2) VMC6; BAR;
    // ph5: compute buf1
    READ_B32(1) READ_A32(1, 0, aLo)
    STAGE_A(0, 1, tN0)
    BAR; LGKM0; MFMA8(0, aLo, 0) BAR;
    // ph6
    READ_A32(1, 2, aHi)
    STAGE_B(1, 0, tN1)
    BAR; LGKM0; MFMA8(2, aHi, 0) BAR;
    // ph7
    STAGE_B(1, 1, tN1)
    BAR; MFMA8(0, aLo, 2) BAR;
    // ph8: counted wait -> buf0 (tile tN0) complete
    STAGE_A(1, 0, tN1)
    BAR; MFMA8(2, aHi, 2) VMC6; BAR;
  }
  // epilogue iteration (tiles tb+106 buf0, tb+107 buf1)
  {
    READ_B32(0) READ_A32(0, 0, aLo)
    STAGE_A(1, 1, tb + 107)
    BAR; LGKM0; MFMA8(0, aLo, 0) BAR;
    READ_A32(0, 2, aHi)
    BAR; LGKM0; MFMA8(2, aHi, 0) BAR;
    BAR; MFMA8(0, aLo, 2) BAR;
    BAR; MFMA8(2, aHi, 2) VMC0; BAR;
    READ_B32(1) READ_A32(1, 0, aLo)
    BAR; LGKM0; MFMA8(0, aLo, 0) BAR;
    READ_A32(1, 2, aHi)
    BAR; LGKM0; MFMA8(2, aHi, 0) BAR;
    BAR; MFMA8(0, aLo, 2) BAR;
    BAR; MFMA8(2, aHi, 2) BAR;
  }

  // epilogue: C/D layout col=lane&31, row=(reg&3)+8*(reg>>2)+4*(lane>>5)
  bf16_t* __restrict__ P = Pb + (((size_t)(slice << 1) + side) << 21);
#pragma unroll
  for (int tm = 0; tm < 4; ++tm) {
#pragma unroll
    for (int tn = 0; tn < 2; ++tn) {
#pragma unroll
      for (int rg = 0; rg < 16; ++rg) {
        const int row = m0 + (wm << 7) + (tm << 5) + (rg & 3) + ((rg >> 2) << 3) + (laneh << 2);
        const int col = n0 + (wn << 6) + (tn << 5) + lane31;
        P[((size_t)row << 11) + col] = (bf16_t)acc[tm][tn][rg];
      }
    }
  }
}

// -------------------------------- split-K reduce + bias + GN partial stats
__global__ __launch_bounds__(256) void reduce4_kernel(
    const bf16_t* __restrict__ Pb, const float* __restrict__ bias_l,
    const float* __restrict__ bias_r, bf16_t* __restrict__ out_l, bf16_t* __restrict__ out_r,
    float* __restrict__ pS_lr, float* __restrict__ pQ_lr)
{
  const int id = blockIdx.x * 256 + threadIdx.x;
  const int tid = threadIdx.x;
  const int c8 = id & 255;
  const int co = (id >> 8) & 1023;
  const int side = id >> 18;
  const size_t off = ((size_t)co << 11) + ((size_t)c8 << 3);
  const float bia = (side ? bias_r : bias_l)[co];
  float acc[8];
#pragma unroll
  for (int e = 0; e < 8; ++e) acc[e] = bia;
#pragma unroll
  for (int s = 0; s < 4; ++s) {
    const bf16x8 v = *(const bf16x8*)&Pb[(((size_t)(s << 1) + side) << 21) + off];
#pragma unroll
    for (int e = 0; e < 8; ++e) acc[e] += (float)v[e];
  }
  bf16x8 ov;
#pragma unroll
  for (int e = 0; e < 8; ++e) ov[e] = (bf16_t)acc[e];
  *(bf16x8*)((side ? out_r : out_l) + off) = ov;
  float s = 0.f, q = 0.f;
#pragma unroll
  for (int e = 0; e < 8; ++e) { s += acc[e]; q += acc[e] * acc[e]; }
  __shared__ float sb[8];
  const int lane = tid & 63, wv = tid >> 6;
#pragma unroll
  for (int o = 1; o < 64; o <<= 1) { s += __shfl_xor(s, o, 64); q += __shfl_xor(q, o, 64); }
  if (lane == 0) { sb[wv] = s; sb[4 + wv] = q; }
  __syncthreads();
  if (tid == 0) {
    const int g = (side << 6) + (co >> 5);
    atomicAdd(&pS_lr[g],      sb[0] + sb[1]);
    atomicAdd(&pS_lr[g + 32], sb[2] + sb[3]);
    atomicAdd(&pQ_lr[g],      sb[4] + sb[5]);
    atomicAdd(&pQ_lr[g + 32], sb[6] + sb[7]);
  }
}

// ------------------------------------------------------- shared GEMM accum
__device__ __forceinline__ void gemm_accum(
    const bf16_t* __restrict__ A, int lda,
    const bf16_t* __restrict__ Bt, int ldb,
    int K, f32x4 acc[4][4])
{
  __shared__ bf16_t Asm[128 * 64];
  __shared__ bf16_t Bsm[128 * 64];
  const int tid = threadIdx.x;
  const int lane = tid & 63;
  const int wv = tid >> 6;
  const int wm = wv >> 1, wn = wv & 1;
  const int lane15 = lane & 15, lane4 = lane >> 4;
  const int srow0 = (wv << 5) + (lane >> 3);
  const int sc = lane & 7;

  for (int k0 = 0; k0 < K; k0 += 64) {
#pragma unroll
    for (int i = 0; i < 4; ++i) {
      const int row = srow0 + (i << 3);
      gload_lds16(A + (size_t)row * lda + k0 + ((sc ^ (row & 7)) << 3),
                  &Asm[((wv << 2) + i) << 9]);
    }
#pragma unroll
    for (int i = 0; i < 4; ++i) {
      const int row = srow0 + (i << 3);
      gload_lds16(Bt + (size_t)row * ldb + k0 + ((sc ^ (row & 7)) << 3),
                  &Bsm[((wv << 2) + i) << 9]);
    }
    __syncthreads();
#pragma unroll
    for (int ks = 0; ks < 2; ++ks) {
      bf16x8 af[4];
#pragma unroll
      for (int mi = 0; mi < 4; ++mi) {
        const int row = (wm << 6) + (mi << 4) + lane15;
        const int ch = ((ks << 2) + lane4) ^ (row & 7);
        af[mi] = *(const bf16x8*)&Asm[(row << 6) + (ch << 3)];
      }
#pragma unroll
      for (int ni = 0; ni < 4; ++ni) {
        const int row = (wn << 6) + (ni << 4) + lane15;
        const int ch = ((ks << 2) + lane4) ^ (row & 7);
        const bf16x8 bfr = *(const bf16x8*)&Bsm[(row << 6) + (ch << 3)];
#pragma unroll
        for (int mi = 0; mi < 4; ++mi)
          acc[mi][ni] = mfma16(af[mi], bfr, acc[mi][ni]);
      }
    }
    __syncthreads();
  }
}

// --------------- merged projections: qk (transposed out) + v, one dispatch
struct ProjAllArgs {
  const bf16_t* act[2];          // flT, rfT
  const float*  bias[2][2];      // [side][seg]: ql,kl / kr,qr
  float         scl[2][2];
  bf16_t*       outp[2][2];      // qlT,klT / krT,qrT
  const float*  vbias[2];        // vlb, vrb
  bf16_t*       vout[2];         // Vl, Vr
};
__global__ __launch_bounds__(256) void proj_all_kernel(const bf16_t* __restrict__ Wp, ProjAllArgs a)
{
  const int bid = blockIdx.x;
  const bool qk = bid < 512;
  int side, m0, n0;
  const bf16_t* Ap;
  const bf16_t* Bp;
  if (qk) {
    side = bid >> 8;
    const int rem = bid & 255;
    n0 = (rem & 15) << 7;          // activation rows
    m0 = (rem >> 4) << 7;          // stacked q/k rows
    Ap = a.act[side] + (size_t)n0 * 1024;
    Bp = Wp + (size_t)side * 2097152 + (size_t)m0 * 1024;
  } else {
    const int u = bid - 512;
    side = u >> 7;
    const int rem = u & 127;
    m0 = (rem & 7) << 7;           // v output rows
    n0 = (rem >> 3) << 7;          // activation rows
    Ap = Wp + 4194304ull + (size_t)side * 1048576 + (size_t)m0 * 1024;
    Bp = a.act[side] + (size_t)n0 * 1024;
  }

  const f32x4 fz = {0.f, 0.f, 0.f, 0.f};
  f32x4 acc[4][4];
#pragma unroll
  for (int i = 0; i < 4; ++i)
#pragma unroll
    for (int j = 0; j < 4; ++j) acc[i][j] = fz;
  gemm_accum(Ap, 1024, Bp, 1024, 1024, acc);

  const int lane = threadIdx.x & 63, wv = threadIdx.x >> 6;
  const int wm = wv >> 1, wn = wv & 1;
  const int lane15 = lane & 15, lane4 = lane >> 4;

  if (qk) {
    const int seg = m0 >> 10;
    const float* __restrict__ bias = a.bias[side][seg];
    const float bscale = a.scl[side][seg];
    bf16_t* __restrict__ C = a.outp[side][seg];
    const int mloc = (m0 & 1023) + (wn << 6);
    float bv[4];
#pragma unroll
    for (int ni = 0; ni < 4; ++ni) bv[ni] = bias[mloc + (ni << 4) + lane15] * bscale;
#pragma unroll
    for (int mi = 0; mi < 4; ++mi) {
      const int rowb = n0 + (wm << 6) + (mi << 4) + (lane4 << 2);
#pragma unroll
      for (int r = 0; r < 4; ++r) {
#pragma unroll
        for (int ni = 0; ni < 4; ++ni) {
          const int col = mloc + (ni << 4) + lane15;
          C[(size_t)(rowb + r) * 1024 + col] = (bf16_t)(acc[mi][ni][r] + bv[ni]);
        }
      }
    }
  } else {
    const float* __restrict__ bias = a.vbias[side];
    bf16_t* __restrict__ C = a.vout[side];
#pragma unroll
    for (int mi = 0; mi < 4; ++mi) {
      const int row0 = m0 + (wm << 6) + (mi << 4) + (lane4 << 2);
#pragma unroll
      for (int r = 0; r < 4; ++r) {
        const float bia = bias[row0 + r];
#pragma unroll
        for (int ni = 0; ni < 4; ++ni) {
          const int col = n0 + (wn << 6) + (ni << 4) + lane15;
          C[(size_t)(row0 + r) * 2048 + col] = (bf16_t)(acc[mi][ni][r] + bia);
        }
      }
    }
  }
}

// ------------------------------------------------- fused proj (split-K x2)
__global__ __launch_bounds__(256) void fused_gemm_kernel(
    const bf16_t* __restrict__ Wf, const bf16_t* __restrict__ Bt, bf16_t* __restrict__ Pf)
{
  const int z = blockIdx.z;
  const int m0 = blockIdx.x << 7;
  const int n0 = blockIdx.y << 7;
  const f32x4 fz = {0.f, 0.f, 0.f, 0.f};
  f32x4 acc[4][4];
#pragma unroll
  for (int i = 0; i < 4; ++i)
#pragma unroll
    for (int j = 0; j < 4; ++j) acc[i][j] = fz;
  gemm_accum(Wf + (size_t)m0 * 1024 + (z << 9), 1024,
             Bt + (size_t)n0 * 1024 + (z << 9), 1024, 512, acc);

  const int lane = threadIdx.x & 63, wv = threadIdx.x >> 6;
  const int wm = wv >> 1, wn = wv & 1;
  const int lane15 = lane & 15, lane4 = lane >> 4;
  bf16_t* __restrict__ C = Pf + ((size_t)z << 22);
#pragma unroll
  for (int mi = 0; mi < 4; ++mi) {
    const int row0 = m0 + (wm << 6) + (mi << 4) + (lane4 << 2);
#pragma unroll
    for (int r = 0; r < 4; ++r) {
#pragma unroll
      for (int ni = 0; ni < 4; ++ni) {
        const int col = n0 + (wn << 6) + (ni << 4) + lane15;
        C[(size_t)(row0 + r) * 4096 + col] = (bf16_t)acc[mi][ni][r];
      }
    }
  }
}

// ------------------------------------ GN (l/r) apply (mu/rstd from partials)
__global__ __launch_bounds__(256) void gn_apply_lr_kernel(
    const bf16_t* __restrict__ yl, const bf16_t* __restrict__ yr,
    const float* __restrict__ gl, const float* __restrict__ bl,
    const float* __restrict__ gr, const float* __restrict__ br,
    const float* __restrict__ pS_lr, const float* __restrict__ pQ_lr,
    bf16_t* __restrict__ flT, bf16_t* __restrict__ rfT)
{
  const int side = blockIdx.z;
  const int n0 = blockIdx.x << 6;
  const int c0 = blockIdx.y << 6;
  const bf16_t* __restrict__ y = side ? yr : yl;
  const float* __restrict__ gamma = side ? gr : gl;
  const float* __restrict__ beta  = side ? br : bl;
  __shared__ float L[64][65];
  const int tid = threadIdx.x;
#pragma unroll
  for (int j = 0; j < 2; ++j) {
    const int u = tid + (j << 8);
    const int cr = u >> 3, ch = u & 7;
    const bf16x8 v = *(const bf16x8*)&y[(size_t)(c0 + cr) * 2048 + n0 + (ch << 3)];
#pragma unroll
    for (int e = 0; e < 8; ++e) L[cr][(ch << 3) + e] = (float)v[e];
  }
  __syncthreads();
  const int b = n0 >> 10;
  bf16_t* __restrict__ outT = side ? rfT : flT;
#pragma unroll
  for (int j = 0; j < 2; ++j) {
    const int u = tid + (j << 8);
    const int nr = u >> 3, c8 = u & 7;
    const int n = n0 + nr;
    const int nf = side ? ((n & ~7) | (7 - (n & 7))) : n;
    const int cbase = c0 + (c8 << 3);
    const int gidx = (side << 6) + (b << 5) + (cbase >> 5);
    const float m = pS_lr[gidx] * (1.f / 32768.f);
    const float rs = rsqrtf(pQ_lr[gidx] * (1.f / 32768.f) - m * m + 1e-5f);
    bf16x8 v;
#pragma unroll
    for (int e = 0; e < 8; ++e) {
      const int c = cbase + e;
      const float xv = (L[(c8 << 3) + e][nr] - m) * rs * gamma[c] + beta[c];
      v[e] = (bf16_t)fmaxf(xv, 0.f);
    }
    *(bf16x8*)&outT[(size_t)nf * 1024 + cbase] = v;
  }
}

// --------------------------------------------------------------- attention
#define ATTN_STAGE(IT, BUF)                                                   \
  _Pragma("unroll")                                                           \
  for (int j_ = 0; j_ < 4; ++j_) {                                            \
    const int g_ = (wv << 2) + j_;                                            \
    const int row_ = (g_ << 2) + lane4;                                       \
    gload_lds16(kt + (size_t)((b << 10) + ((IT) << 6) + row_) * 1024 + (h << 7) + ((lane15 ^ (row_ & 7)) << 3), \
                &Ks[BUF][g_ << 9]);                                           \
  }                                                                           \
  _Pragma("unroll")                                                           \
  for (int j_ = 0; j_ < 4; ++j_) {                                            \
    const int g_ = (wv << 2) + j_;                                            \
    const int row_ = (g_ << 3) + (lane >> 3);                                 \
    gload_lds16(vm + (size_t)((h << 7) + row_) * 2048 + (b << 10) + ((IT) << 6) + (((lane & 7) ^ (row_ & 7)) << 3), \
                &Vs[BUF][g_ << 9]);                                           \
  }

__global__ __launch_bounds__(256, 2) void attn_kernel(
    const bf16_t* __restrict__ qlt, const bf16_t* __restrict__ krt, const bf16_t* __restrict__ vrm,
    const bf16_t* __restrict__ qrt, const bf16_t* __restrict__ klt, const bf16_t* __restrict__ vlm,
    bf16_t* __restrict__ xfc)
{
  const int st = blockIdx.x;
  const int bh = blockIdx.y;
  const int az = blockIdx.z;
  const int b = bh >> 3, h = bh & 7;
  const bf16_t* __restrict__ qt = az ? qrt : qlt;
  const bf16_t* __restrict__ kt = az ? klt : krt;
  const bf16_t* __restrict__ vm = az ? vlm : vrm;

  __shared__ bf16_t Ks[2][64 * 128];
  __shared__ bf16_t Vs[2][128 * 64];
  __shared__ bf16_t Ps[4][16 * 64];

  const int tid = threadIdx.x, lane = tid & 63, wv = tid >> 6;
  const int lane15 = lane & 15, lane4 = lane >> 4;

  bf16x8 qf[4];
  {
    const bf16_t* __restrict__ qbase = qt + (size_t)((b << 10) + (st << 6)) * 1024 + (h << 7);
    const int row = (wv << 4) + lane15;
#pragma unroll
    for (int kk = 0; kk < 4; ++kk)
      qf[kk] = *(const bf16x8*)&qbase[(size_t)row * 1024 + (kk << 5) + (lane4 << 3)];
  }

  const f32x4 fz = {0.f, 0.f, 0.f, 0.f};
  f32x4 oacc[8];
#pragma unroll
  for (int nj = 0; nj < 8; ++nj) oacc[nj] = fz;
  float mrun[4], lrun[4];
#pragma unroll
  for (int r = 0; r < 4; ++r) { mrun[r] = -3.0e38f; lrun[r] = 0.f; }

  ATTN_STAGE(0, 0)
  ATTN_STAGE(1, 1)

  for (int it = 0; it < 16; ++it) {
    const int cur = it & 1;
    if (it < 15) { asm volatile("s_waitcnt vmcnt(8)" ::: "memory"); }
    else         { asm volatile("s_waitcnt vmcnt(0)" ::: "memory"); }
    __builtin_amdgcn_s_barrier();
    f32x4 la[4];
#pragma unroll
    for (int tj = 0; tj < 4; ++tj) la[tj] = fz;
#pragma unroll
    for (int kk = 0; kk < 4; ++kk) {
#pragma unroll
      for (int tj = 0; tj < 4; ++tj) {
        const int row = (tj << 4) + lane15;
        const int ch = ((kk << 2) + lane4) ^ (row & 7);
        const bf16x8 kf = *(const bf16x8*)&Ks[cur][(row << 7) + (ch << 3)];
        la[tj] = mfma16(qf[kk], kf, la[tj]);
      }
    }
    float mx[4];
    int ok = 1;
#pragma unroll
    for (int r = 0; r < 4; ++r) {
      float m_ = la[0][r];
#pragma unroll
      for (int tj = 1; tj < 4; ++tj) m_ = fmaxf(m_, la[tj][r]);
#pragma unroll
      for (int o = 1; o < 16; o <<= 1) m_ = fmaxf(m_, __shfl_xor(m_, o, 64));
      mx[r] = m_;
      ok &= (m_ <= mrun[r] + 8.f) ? 1 : 0;
    }
    if (!__all(ok)) {
#pragma unroll
      for (int r = 0; r < 4; ++r) {
        const float mnew = fmaxf(mrun[r], mx[r]);
        const float alpha = __builtin_amdgcn_exp2f(mrun[r] - mnew);
        mrun[r] = mnew;
        lrun[r] *= alpha;
#pragma unroll
        for (int nj = 0; nj < 8; ++nj) oacc[nj][r] *= alpha;
      }
    }
#pragma unroll
    for (int r = 0; r < 4; ++r) {
      const int row = (lane4 << 2) + r;
      float rs = 0.f;
#pragma unroll
      for (int tj = 0; tj < 4; ++tj) {
        const float p = __builtin_amdgcn_exp2f(la[tj][r] - mrun[r]);
        rs += p;
        const int byte_ = ((tj << 5) + (lane15 << 1)) ^ ((row & 7) << 4);
        *(bf16_t*)((char*)(&Ps[wv][0]) + (row << 7) + byte_) = (bf16_t)p;
      }
#pragma unroll
      for (int o = 1; o < 16; o <<= 1) rs += __shfl_xor(rs, o, 64);
      lrun[r] += rs;
    }
#pragma unroll
    for (int kk = 0; kk < 2; ++kk) {
      const int prow = lane15;
      const int pch = ((kk << 2) + lane4) ^ (prow & 7);
      const bf16x8 pf = *(const bf16x8*)&Ps[wv][(prow << 6) + (pch << 3)];
#pragma unroll
      for (int nj = 0; nj < 8; ++nj) {
        const int row = (nj << 4) + lane15;
        const int ch = ((kk << 2) + lane4) ^ (row & 7);
        const bf16x8 vf = *(const bf16x8*)&Vs[cur][(row << 6) + (ch << 3)];
        oacc[nj] = mfma16(pf, vf, oacc[nj]);
      }
    }
    __builtin_amdgcn_s_barrier();
    if (it + 2 < 16) { ATTN_STAGE(it + 2, cur) }
  }
#pragma unroll
  for (int r = 0; r < 4; ++r) {
    const int sl = (wv << 4) + (lane4 << 2) + r;
    const int s = (st << 6) + sl;
    const int dd = s >> 7, hh2 = (s >> 3) & 15, ww = s & 7;
    const int w16 = az ? (15 - ww) : ww;
    const int n16 = (b << 11) + ((dd << 4) + hh2) * 16 + w16;
    const float inv = 1.f / lrun[r];
#pragma unroll
    for (int nj = 0; nj < 8; ++nj) {
      const int c = (h << 7) + (nj << 4) + lane15;
      xfc[(size_t)n16 * 1024 + c] = (bf16_t)(oacc[nj][r] * inv);
    }
  }
}

// -------------------------------------------------------------- GN (fused)
__global__ __launch_bounds__(256) void gn_partial_f_kernel(
    const bf16_t* __restrict__ Pf, const float* __restrict__ bias,
    float* __restrict__ pS, float* __restrict__ pQ)
{
  const int bg = blockIdx.x;
  const int sl = blockIdx.y;
  const int b = bg >> 5, g = bg & 31;
  const int tid = threadIdx.x;
  const int c = (g << 5) + (tid >> 3);
  const int s0 = (sl << 8) + ((tid & 7) << 5);
  const size_t base = (size_t)c * 4096 + (b << 11) + s0;
  const float bia = bias[c];
  float s = 0.f, q = 0.f;
#pragma unroll
  for (int u = 0; u < 4; ++u) {
    const bf16x8 v0 = *(const bf16x8*)&Pf[base + (u << 3)];
    const bf16x8 v1 = *(const bf16x8*)&Pf[base + (u << 3) + 4194304];
#pragma unroll
    for (int e = 0; e < 8; ++e) {
      const float v = (float)v0[e] + (float)v1[e] + bia;
      s += v; q += v * v;
    }
  }
  __shared__ float sb[8];
  const int lane = tid & 63, wv = tid >> 6;
#pragma unroll
  for (int o = 1; o < 64; o <<= 1) { s += __shfl_xor(s, o, 64); q += __shfl_xor(q, o, 64); }
  if (lane == 0) { sb[wv] = s; sb[4 + wv] = q; }
  __syncthreads();
  if (tid == 0) {
    pS[(bg << 3) + sl] = sb[0] + sb[1] + sb[2] + sb[3];
    pQ[(bg << 3) + sl] = sb[4] + sb[5] + sb[6] + sb[7];
  }
}

__global__ __launch_bounds__(256) void gn_apply_f_kernel(
    const bf16_t* __restrict__ Pf, const float* __restrict__ bias,
    const float* __restrict__ gamma, const float* __restrict__ beta,
    const float* __restrict__ pS, const float* __restrict__ pQ,
    float* __restrict__ outp)
{
  const int id = blockIdx.x * 256 + threadIdx.x;
  const int s8 = id & 255;
  const int c = (id >> 8) & 1023;
  const int b = id >> 18;
  const int gidx = (b << 5) + (c >> 5);
  float S = 0.f, Q = 0.f;
#pragma unroll
  for (int sl = 0; sl < 8; ++sl) { S += pS[(gidx << 3) + sl]; Q += pQ[(gidx << 3) + sl]; }
  const float m = S * (1.f / 65536.f);
  const float rs = rsqrtf(Q * (1.f / 65536.f) - m * m + 1e-5f);
  const float gm = gamma[c], bt = beta[c], bia = bias[c];
  const size_t idx = (size_t)c * 4096 + (b << 11) + (s8 << 3);
  const bf16x8 v0 = *(const bf16x8*)&Pf[idx];
  const bf16x8 v1 = *(const bf16x8*)&Pf[idx + 4194304];
  float o[8];
#pragma unroll
  for (int e = 0; e < 8; ++e) {
    const float v = (float)v0[e] + (float)v1[e] + bia;
    o[e] = fmaxf((v - m) * rs * gm + bt, 0.f);
  }
  float* __restrict__ op = &outp[(((size_t)(b << 10) + c) << 11) + (s8 << 3)];
  float4 o0, o1;
  o0.x = o[0]; o0.y = o[1]; o0.z = o[2]; o0.w = o[3];
  o1.x = o[4]; o1.y = o[5]; o1.z = o[6]; o1.w = o[7];
  *(float4*)op = o0;
  *(float4*)(op + 4) = o1;
}

// ------------------------------------------------------------------- asym
__global__ __launch_bounds__(256) void asym_kernel(
    const bf16_t* __restrict__ flT, const bf16_t* __restrict__ rfT, float* __restrict__ outp)
{
  const int n = blockIdx.x;
  const int tid = threadIdx.x;
  const bf16x4 a = *(const bf16x4*)&flT[(size_t)n * 1024 + (tid << 2)];
  const bf16x4 c = *(const bf16x4*)&rfT[(size_t)n * 1024 + (tid << 2)];
  float s = 0.f;
#pragma unroll
  for (int e = 0; e < 4; ++e) s += fabsf((float)a[e] - (float)c[e]);
  __shared__ float sb[4];
  const int lane = tid & 63, wv = tid >> 6;
#pragma unroll
  for (int o = 1; o < 64; o <<= 1) s += __shfl_xor(s, o, 64);
  if (lane == 0) sb[wv] = s;
  __syncthreads();
  if (tid == 0) outp[n] = (sb[0] + sb[1] + sb[2] + sb[3]) * (1.f / 1024.f);
}

// ================================================================== launch
extern "C" void kernel_launch(void* const* d_in, const int* in_sizes, int n_in,
                              void* d_out, int out_size, void* d_ws, size_t ws_size,
                              hipStream_t stream)
{
  (void)in_sizes; (void)n_in; (void)out_size; (void)ws_size;
  const float* x    = (const float*)d_in[0];
  const float* clw  = (const float*)d_in[1];
  const float* clb  = (const float*)d_in[2];
  const float* glg  = (const float*)d_in[3];
  const float* glb_ = (const float*)d_in[4];
  const float* crw  = (const float*)d_in[5];
  const float* crb  = (const float*)d_in[6];
  const float* grg  = (const float*)d_in[7];
  const float* grb  = (const float*)d_in[8];
  const float* qlw = (const float*)d_in[9];  const float* qlb = (const float*)d_in[10];
  const float* krw = (const float*)d_in[11]; const float* krb = (const float*)d_in[12];
  const float* vrw = (const float*)d_in[13]; const float* vrb = (const float*)d_in[14];
  const float* qrw = (const float*)d_in[15]; const float* qrb = (const float*)d_in[16];
  const float* klw = (const float*)d_in[17]; const float* klb = (const float*)d_in[18];
  const float* vlw = (const float*)d_in[19]; const float* vlb = (const float*)d_in[20];
  const float* fuw = (const float*)d_in[21]; const float* fub = (const float*)d_in[22];
  const float* gfg = (const float*)d_in[23]; const float* gfb = (const float*)d_in[24];
  float* out = (float*)d_out;

  char* ws = (char*)d_ws;
  size_t off = 0;
  auto take = [&](size_t bytes) -> char* {
    char* p = ws + off; off += (bytes + 255) & ~(size_t)255; return p;
  };
  bf16_t* Wb    = (bf16_t*)take(113246208ull);   // 2 x [1024][27648] bf16
  bf16_t* Wp    = (bf16_t*)take(14680064ull);    // 7 x [1024][1024] bf16 (stacked)
  bf16_t* Xp    = (bf16_t*)take(14745600ull);    // padded input bf16
  float*  pS_lr = (float*) take(512);            // contiguous with Xp: one memset
  float*  pQ_lr = (float*) take(512);
  bf16_t* convL = (bf16_t*)take(4194304ull);     // [1024][2048] bf16
  bf16_t* convR = (bf16_t*)take(4194304ull);
  bf16_t* flT   = (bf16_t*)take(4194304ull);     // [2048][1024]
  bf16_t* rfT   = (bf16_t*)take(4194304ull);
  float*  pS    = (float*) take(2048);
  float*  pQ    = (float*) take(2048);
  bf16_t* Pb    = (bf16_t*)take(33554432ull);    // 4 x 2 x [1024][2048] bf16 partials

  char* al = (char*)Wb; size_t aoff = 0;
  auto takeA = [&](size_t bytes) -> char* {
    char* p = al + aoff; aoff += (bytes + 255) & ~(size_t)255; return p;
  };
  bf16_t* qlT = (bf16_t*)takeA(4194304ull);      // [2048][1024]
  bf16_t* klT = (bf16_t*)takeA(4194304ull);
  bf16_t* krT = (bf16_t*)takeA(4194304ull);
  bf16_t* qrT = (bf16_t*)takeA(4194304ull);
  bf16_t* Vl  = (bf16_t*)takeA(4194304ull);      // [1024][2048]
  bf16_t* Vr  = (bf16_t*)takeA(4194304ull);
  bf16_t* xfcT = (bf16_t*)takeA(8388608ull);     // [4096][1024]
  bf16_t* Pf   = (bf16_t*)takeA(16777216ull);    // 2 x [1024][4096] bf16 split-K partials

  const float QS = 0.08838834764831843f * 1.4426950408889634f;  // SCALE * log2(e)

  hipMemsetAsync(Xp, 0, 14745600ull + 1024ull, stream);
  convw_kernel<<<dim3(4, 1024, 2), 256, 0, stream>>>(clw, crw, Wb);
  projw_kernel<<<dim3(1024, 7), 256, 0, stream>>>(qlw, klw, krw, qrw, vlw, vrw, fuw, Wp, QS);
  xp_build_kernel<<<dim3(16, 8, 4), 256, 0, stream>>>(x, Xp);
  conv8_kernel<<<dim3(256), 512, 0, stream>>>(Wb, Xp, Pb);
  reduce4_kernel<<<dim3(2048), 256, 0, stream>>>(Pb, clb, crb, convL, convR, pS_lr, pQ_lr);
  gn_apply_lr_kernel<<<dim3(32, 16, 2), 256, 0, stream>>>(convL, convR, glg, glb_, grg, grb,
                                                          pS_lr, pQ_lr, flT, rfT);
  ProjAllArgs pa;
  pa.act[0] = flT; pa.act[1] = rfT;
  pa.bias[0][0] = qlb; pa.bias[0][1] = klb;
  pa.bias[1][0] = krb; pa.bias[1][1] = qrb;
  pa.scl[0][0] = QS;  pa.scl[0][1] = 1.f;
  pa.scl[1][0] = 1.f; pa.scl[1][1] = QS;
  pa.outp[0][0] = qlT; pa.outp[0][1] = klT;
  pa.outp[1][0] = krT; pa.outp[1][1] = qrT;
  pa.vbias[0] = vlb; pa.vbias[1] = vrb;
  pa.vout[0] = Vl;   pa.vout[1] = Vr;
  proj_all_kernel<<<dim3(768), 256, 0, stream>>>(Wp, pa);

  attn_kernel<<<dim3(16, 16, 2), 256, 0, stream>>>(qlT, krT, Vr, qrT, klT, Vl, xfcT);
  fused_gemm_kernel<<<dim3(8, 32, 2), 256, 0, stream>>>(Wp + 6ull * 1048576, xfcT, Pf);
  gn_partial_f_kernel<<<dim3(64, 8), 256, 0, stream>>>(Pf, fub, pS, pQ);
  gn_apply_f_kernel<<<dim3(2048), 256, 0, stream>>>(Pf, fub, gfg, gfb, pS, pQ, out);
  asym_kernel<<<dim3(2048), 256, 0, stream>>>(flT, rfT, out + 4194304);
}

// Round 13
// 437.135 us; speedup vs baseline: 1.0911x; 1.0911x over previous
//
#include <hip/hip_runtime.h>
#include <hip/hip_bf16.h>
#include <stdint.h>

// SymmetryAwareBottleneck: conv3x3x3 (x2, implicit GEMM, split-K x4 even 108
// K-tiles/slice, 8-phase 256x256 burst-read counted-vmcnt(6) schedule) -> GN
// (stats folded into split-K reduce) -> relu -> merged proj (qk-transposed + v,
// one 768-block dispatch) -> 2 flash attns (QBLK=64, defer-max, double-buffered
// KV, counted vmcnt(8)) -> fused proj (split-K x2, reduce folded into GN) ->
// GN -> relu ; asym map.

using bf16_t = __bf16;
using bf16x4 = __attribute__((ext_vector_type(4))) __bf16;
using bf16x8 = __attribute__((ext_vector_type(8))) __bf16;
using f32x4  = __attribute__((ext_vector_type(4))) float;

typedef const uint32_t __attribute__((address_space(1)))* gas1_t;
typedef uint32_t __attribute__((address_space(3)))* las3_t;

__device__ __forceinline__ f32x4 mfma16(bf16x8 a, bf16x8 b, f32x4 c) {
  return __builtin_amdgcn_mfma_f32_16x16x32_bf16(a, b, c, 0, 0, 0);
}
__device__ __forceinline__ void gload_lds16(const void* g, void* l) {
  __builtin_amdgcn_global_load_lds((gas1_t)g, (las3_t)l, 16, 0, 0);
}

// ---------------------------------------------------------------- weight cvt
__global__ __launch_bounds__(256) void convw_kernel(
    const float* __restrict__ wl, const float* __restrict__ wr,
    bf16_t* __restrict__ Wb)
{
  const int chunk = blockIdx.x;            // 0..3  (256 ci each)
  const int co    = blockIdx.y;            // 0..1023
  const int side  = blockIdx.z;
  const float* __restrict__ src = (side ? wr : wl) + (size_t)co * 27648 + (size_t)chunk * 6912;
  __shared__ float L[6912];                // [256 ci][27 t]
  __shared__ bf16_t Lb[27][260];           // [t][ci] bf16 (padded)
  const int tid = threadIdx.x;
  for (int i = tid; i < 1728; i += 256)
    *(float4*)&L[i << 2] = *(const float4*)&src[i << 2];
  __syncthreads();
  {
    const int ci = tid;
#pragma unroll
    for (int t = 0; t < 27; ++t)
      Lb[t][ci] = (bf16_t)L[ci * 27 + t];
  }
  __syncthreads();
  bf16_t* __restrict__ dst = Wb + (size_t)side * (1024u * 27648u) + (size_t)co * 27648 + (chunk << 8);
  for (int u = tid; u < 864; u += 256) {
    const int t = u >> 5, c8 = (u & 31) << 3;
    const bf16x8 v = *(const bf16x8*)&Lb[t][c8];
    *(bf16x8*)&dst[(t << 10) + c8] = v;
  }
}

// proj weights fp32->bf16, stacked: z = ql(QS), kl, kr, qr(QS), vl, vr, fus
__global__ __launch_bounds__(256) void projw_kernel(
    const float* ql, const float* kl, const float* kr, const float* qr,
    const float* vl, const float* vr, const float* fu,
    bf16_t* __restrict__ Wp, float qs)
{
  const int z = blockIdx.y;
  const float* src; float s = 1.f;
  switch (z) {
    case 0: src = ql; s = qs; break;
    case 1: src = kl; break;
    case 2: src = kr; break;
    case 3: src = qr; s = qs; break;
    case 4: src = vl; break;
    case 5: src = vr; break;
    default: src = fu; break;
  }
  const size_t i4 = ((size_t)blockIdx.x * 256 + threadIdx.x) * 4;
  const float4 v = *(const float4*)(src + i4);
  bf16x4 o;
  o[0] = (bf16_t)(v.x * s); o[1] = (bf16_t)(v.y * s);
  o[2] = (bf16_t)(v.z * s); o[3] = (bf16_t)(v.w * s);
  *(bf16x4*)(Wp + (size_t)z * 1048576 + i4) = o;
}

// ------------------------------------------------------------- padded input
__global__ __launch_bounds__(256) void xp_build_kernel(
    const float* __restrict__ x, bf16_t* __restrict__ Xp)
{
  const int cc0  = blockIdx.x << 6;
  const int d    = blockIdx.y;
  const int sb   = blockIdx.z;
  const int side = sb >> 1, b = sb & 1;
  __shared__ bf16_t Tls[64][132];
  const int tid = threadIdx.x;
#pragma unroll
  for (int j = 0; j < 8; ++j) {
    const int u = tid + (j << 8);
    const int ci = u >> 5, sub = u & 31;
    const int hh = sub >> 1, half = sub & 1;
    const float4 v = *(const float4*)&x[((size_t)((b << 10) + cc0 + ci) * 8 + d) * 256 +
                                        (hh << 4) + (side << 3) + (half << 2)];
    bf16x4 o;
    o[0] = (bf16_t)v.x; o[1] = (bf16_t)v.y; o[2] = (bf16_t)v.z; o[3] = (bf16_t)v.w;
    *(bf16x4*)&Tls[ci][(hh << 3) + (half << 2)] = o;
  }
  __syncthreads();
  bf16_t* __restrict__ dst = Xp + (size_t)side * 3686400 + (size_t)b * 1843200;
#pragma unroll
  for (int j = 0; j < 4; ++j) {
    const int u = tid + (j << 8);
    const int hw = u >> 3, c8 = u & 7;
    const int hh = hw >> 3, ww = hw & 7;
    bf16x8 v;
#pragma unroll
    for (int e = 0; e < 8; ++e) v[e] = Tls[(c8 << 3) + e][hw];
    *(bf16x8*)&dst[(size_t)(((d + 1) * 18 + (hh + 1)) * 10 + (ww + 1)) * 1024 + cc0 + (c8 << 3)] = v;
  }
}

// --------------------------------------------------------- conv implicit GEMM
// 8-phase 256x256, BK=64, 8 waves, 128KB LDS dbuf. Burst LDS reads (ph1/2/5/6
// only; ph3/4/7/8 pure-register MFMA, no lgkm wait), counted vmcnt(6) at
// ph4/ph8. Split-K x4 over GLOBAL K-tiles (432 = 27 taps x 16), 108/slice.
#define STAGE_A(BUF, H, TILE)                                                 \
  { const int koff_ = (TILE) << 6;                                            \
    gload_lds16(A + (size_t)arow[H][0] * 27648 + koff_ + swz,                 \
                &Al[BUF][((H) * 128 + (wv << 4)) << 6]);                      \
    gload_lds16(A + (size_t)arow[H][1] * 27648 + koff_ + swz,                 \
                &Al[BUF][(((H) * 128 + (wv << 4)) + 8) << 6]); }

#define STAGE_B(BUF, H, TILE)                                                 \
  { const int t_ = (TILE) >> 4;                                               \
    const int tofs_ = ((t_ / 9) * 18 + ((t_ / 3) % 3)) * 10 + (t_ % 3);       \
    const int cb64_ = ((TILE) & 15) << 6;                                     \
    gload_lds16(X + (size_t)(browbase[H][0] + tofs_) * 1024 + cb64_ + swz,    \
                &Bl[BUF][((H) * 128 + (wv << 4)) << 6]);                      \
    gload_lds16(X + (size_t)(browbase[H][1] + tofs_) * 1024 + cb64_ + swz,    \
                &Bl[BUF][(((H) * 128 + (wv << 4)) + 8) << 6]); }

#define READ_B(BUF)                                                           \
  _Pragma("unroll")                                                           \
  for (int n_ = 0; n_ < 4; ++n_) {                                            \
    const int row_ = (wn << 6) + (n_ << 4) + lane15;                          \
    const int c0_ = lane4 ^ (row_ & 7);                                       \
    const int c1_ = (4 + lane4) ^ (row_ & 7);                                 \
    b0[n_] = *(const bf16x8*)&Bl[BUF][(row_ << 6) + (c0_ << 3)];              \
    b1[n_] = *(const bf16x8*)&Bl[BUF][(row_ << 6) + (c1_ << 3)];              \
  }

#define READ_A(BUF, MBASE, D0, D1)                                           \
  _Pragma("unroll")                                                           \
  for (int m_ = 0; m_ < 4; ++m_) {                                            \
    const int row_ = (wm << 7) + (((MBASE) + m_) << 4) + lane15;              \
    const int c0_ = lane4 ^ (row_ & 7);                                       \
    const int c1_ = (4 + lane4) ^ (row_ & 7);                                 \
    D0[m_] = *(const bf16x8*)&Al[BUF][(row_ << 6) + (c0_ << 3)];              \
    D1[m_] = *(const bf16x8*)&Al[BUF][(row_ << 6) + (c1_ << 3)];              \
  }

#define MFMAQ(MBASE, AR, BR)                                                  \
  __builtin_amdgcn_s_setprio(1);                                              \
  _Pragma("unroll")                                                           \
  for (int m_ = 0; m_ < 4; ++m_)                                              \
    _Pragma("unroll")                                                         \
    for (int n_ = 0; n_ < 4; ++n_)                                            \
      acc[(MBASE) + m_][n_] = mfma16(AR[m_], BR[n_], acc[(MBASE) + m_][n_]);  \
  __builtin_amdgcn_s_setprio(0);

#define BAR __builtin_amdgcn_s_barrier()
#define LGKM0 asm volatile("s_waitcnt lgkmcnt(0)" ::: "memory")
#define VMC6 asm volatile("s_waitcnt vmcnt(6)" ::: "memory")
#define VMC0 asm volatile("s_waitcnt vmcnt(0)" ::: "memory")

__global__ __launch_bounds__(512, 2) void conv8_kernel(
    const bf16_t* __restrict__ Wb, const bf16_t* __restrict__ Xp,
    bf16_t* __restrict__ Pb)
{
  const int bid = blockIdx.x;
  const int orig = (bid & 7) * 32 + (bid >> 3);   // each XCD owns one (slice,side)
  const int ntile = orig & 7;
  const int mtile = (orig >> 3) & 3;
  const int side  = (orig >> 5) & 1;
  const int slice = orig >> 6;
  const int tb = slice * 108;                     // global K-tile base (432 total)
  const int n0 = ntile << 8;
  const int m0 = mtile << 8;
  const int b = n0 >> 10;

  const bf16_t* __restrict__ A = Wb + (size_t)side * 28311552u;
  const bf16_t* __restrict__ X = Xp + (size_t)side * 3686400 + (size_t)b * 1843200;

  __shared__ bf16_t Al[2][256 * 64];
  __shared__ bf16_t Bl[2][256 * 64];

  const int tid = threadIdx.x;
  const int lane = tid & 63;
  const int wv = tid >> 6;                 // 0..7
  const int wm = wv >> 2, wn = wv & 3;     // 2M x 4N
  const int lane15 = lane & 15, lane4 = lane >> 4;
  const int l8 = lane >> 3, l7 = lane & 7;
  const int swz = (l7 ^ l8) << 3;          // pre-swizzled source chunk offset

  int arow[2][2], browbase[2][2];
#pragma unroll
  for (int h = 0; h < 2; ++h)
#pragma unroll
    for (int j = 0; j < 2; ++j) {
      const int r = h * 128 + (wv << 4) + (j << 3) + l8;
      arow[h][j] = m0 + r;
      const int c = n0 + r;
      const int d = (c >> 7) & 7, hh = (c >> 3) & 15, ww = c & 7;
      browbase[h][j] = (d * 18 + hh) * 10 + ww;
    }

  const f32x4 fz = {0.f, 0.f, 0.f, 0.f};
  f32x4 acc[8][4];
#pragma unroll
  for (int i = 0; i < 8; ++i)
#pragma unroll
    for (int j = 0; j < 4; ++j) acc[i][j] = fz;
  bf16x8 b0[4], b1[4], a0k0[4], a0k1[4], a4k0[4], a4k1[4];

  // prologue: buf0 <- tile tb (4 halves), buf1 <- tile tb+1 (Bh0,Bh1,Ah0)
  STAGE_B(0, 0, tb)
  STAGE_B(0, 1, tb)
  STAGE_A(0, 0, tb)
  STAGE_A(0, 1, tb)
  STAGE_B(1, 0, tb + 1)
  STAGE_B(1, 1, tb + 1)
  STAGE_A(1, 0, tb + 1)
  VMC6;                       // oldest 8 loads (buf0) complete
  BAR;

  for (int i = 0; i < 53; ++i) {
    const int tA = tb + 2 * i + 1, tN0 = tb + 2 * i + 2, tN1 = tb + 2 * i + 3;
    // ph1: burst reads (B both k + A.M0 both k); stage buf1.Ah1(tA)
    READ_B(0) READ_A(0, 0, a0k0, a0k1)
    STAGE_A(1, 1, tA)
    BAR; LGKM0; MFMAQ(0, a0k0, b0) BAR;
    // ph2: A.M4 reads
    READ_A(0, 4, a4k0, a4k1)
    STAGE_B(0, 0, tN0)
    BAR; LGKM0; MFMAQ(4, a4k0, b0) BAR;
    // ph3: pure-register
    STAGE_B(0, 1, tN0)
    BAR; MFMAQ(0, a0k1, b1) BAR;
    // ph4: counted wait -> buf1 (tile tA) complete
    STAGE_A(0, 0, tN0)
    BAR; MFMAQ(4, a4k1, b1) VMC6; BAR;
    // ph5: compute buf1
    READ_B(1) READ_A(1, 0, a0k0, a0k1)
    STAGE_A(0, 1, tN0)
    BAR; LGKM0; MFMAQ(0, a0k0, b0) BAR;
    // ph6
    READ_A(1, 4, a4k0, a4k1)
    STAGE_B(1, 0, tN1)
    BAR; LGKM0; MFMAQ(4, a4k0, b0) BAR;
    // ph7
    STAGE_B(1, 1, tN1)
    BAR; MFMAQ(0, a0k1, b1) BAR;
    // ph8: counted wait -> buf0 (tile tN0) complete
    STAGE_A(1, 0, tN1)
    BAR; MFMAQ(4, a4k1, b1) VMC6; BAR;
  }
  // epilogue iteration (tiles tb+106 buf0, tb+107 buf1)
  {
    READ_B(0) READ_A(0, 0, a0k0, a0k1)
    STAGE_A(1, 1, tb + 107)
    BAR; LGKM0; MFMAQ(0, a0k0, b0) BAR;
    READ_A(0, 4, a4k0, a4k1)
    BAR; LGKM0; MFMAQ(4, a4k0, b0) BAR;
    BAR; MFMAQ(0, a0k1, b1) BAR;
    BAR; MFMAQ(4, a4k1, b1) VMC0; BAR;
    READ_B(1) READ_A(1, 0, a0k0, a0k1)
    BAR; LGKM0; MFMAQ(0, a0k0, b0) BAR;
    READ_A(1, 4, a4k0, a4k1)
    BAR; LGKM0; MFMAQ(4, a4k0, b0) BAR;
    BAR; MFMAQ(0, a0k1, b1) BAR;
    BAR; MFMAQ(4, a4k1, b1) BAR;
  }

  bf16_t* __restrict__ P = Pb + (((size_t)(slice << 1) + side) << 21);
#pragma unroll
  for (int m = 0; m < 8; ++m) {
    const int row0 = m0 + (wm << 7) + (m << 4) + (lane4 << 2);
#pragma unroll
    for (int r = 0; r < 4; ++r) {
#pragma unroll
      for (int n = 0; n < 4; ++n) {
        const int col = n0 + (wn << 6) + (n << 4) + lane15;
        P[((size_t)(row0 + r) << 11) + col] = (bf16_t)acc[m][n][r];
      }
    }
  }
}

// -------------------------------- split-K reduce + bias + GN partial stats
__global__ __launch_bounds__(256) void reduce4_kernel(
    const bf16_t* __restrict__ Pb, const float* __restrict__ bias_l,
    const float* __restrict__ bias_r, bf16_t* __restrict__ out_l, bf16_t* __restrict__ out_r,
    float* __restrict__ pS_lr, float* __restrict__ pQ_lr)
{
  const int id = blockIdx.x * 256 + threadIdx.x;
  const int tid = threadIdx.x;
  const int c8 = id & 255;
  const int co = (id >> 8) & 1023;
  const int side = id >> 18;
  const size_t off = ((size_t)co << 11) + ((size_t)c8 << 3);
  const float bia = (side ? bias_r : bias_l)[co];
  float acc[8];
#pragma unroll
  for (int e = 0; e < 8; ++e) acc[e] = bia;
#pragma unroll
  for (int s = 0; s < 4; ++s) {
    const bf16x8 v = *(const bf16x8*)&Pb[(((size_t)(s << 1) + side) << 21) + off];
#pragma unroll
    for (int e = 0; e < 8; ++e) acc[e] += (float)v[e];
  }
  bf16x8 ov;
#pragma unroll
  for (int e = 0; e < 8; ++e) ov[e] = (bf16_t)acc[e];
  *(bf16x8*)((side ? out_r : out_l) + off) = ov;
  float s = 0.f, q = 0.f;
#pragma unroll
  for (int e = 0; e < 8; ++e) { s += acc[e]; q += acc[e] * acc[e]; }
  __shared__ float sb[8];
  const int lane = tid & 63, wv = tid >> 6;
#pragma unroll
  for (int o = 1; o < 64; o <<= 1) { s += __shfl_xor(s, o, 64); q += __shfl_xor(q, o, 64); }
  if (lane == 0) { sb[wv] = s; sb[4 + wv] = q; }
  __syncthreads();
  if (tid == 0) {
    const int g = (side << 6) + (co >> 5);
    atomicAdd(&pS_lr[g],      sb[0] + sb[1]);
    atomicAdd(&pS_lr[g + 32], sb[2] + sb[3]);
    atomicAdd(&pQ_lr[g],      sb[4] + sb[5]);
    atomicAdd(&pQ_lr[g + 32], sb[6] + sb[7]);
  }
}

// ------------------------------------------------------- shared GEMM accum
__device__ __forceinline__ void gemm_accum(
    const bf16_t* __restrict__ A, int lda,
    const bf16_t* __restrict__ Bt, int ldb,
    int K, f32x4 acc[4][4])
{
  __shared__ bf16_t Asm[128 * 64];
  __shared__ bf16_t Bsm[128 * 64];
  const int tid = threadIdx.x;
  const int lane = tid & 63;
  const int wv = tid >> 6;
  const int wm = wv >> 1, wn = wv & 1;
  const int lane15 = lane & 15, lane4 = lane >> 4;
  const int srow0 = (wv << 5) + (lane >> 3);
  const int sc = lane & 7;

  for (int k0 = 0; k0 < K; k0 += 64) {
#pragma unroll
    for (int i = 0; i < 4; ++i) {
      const int row = srow0 + (i << 3);
      gload_lds16(A + (size_t)row * lda + k0 + ((sc ^ (row & 7)) << 3),
                  &Asm[((wv << 2) + i) << 9]);
    }
#pragma unroll
    for (int i = 0; i < 4; ++i) {
      const int row = srow0 + (i << 3);
      gload_lds16(Bt + (size_t)row * ldb + k0 + ((sc ^ (row & 7)) << 3),
                  &Bsm[((wv << 2) + i) << 9]);
    }
    __syncthreads();
#pragma unroll
    for (int ks = 0; ks < 2; ++ks) {
      bf16x8 af[4];
#pragma unroll
      for (int mi = 0; mi < 4; ++mi) {
        const int row = (wm << 6) + (mi << 4) + lane15;
        const int ch = ((ks << 2) + lane4) ^ (row & 7);
        af[mi] = *(const bf16x8*)&Asm[(row << 6) + (ch << 3)];
      }
#pragma unroll
      for (int ni = 0; ni < 4; ++ni) {
        const int row = (wn << 6) + (ni << 4) + lane15;
        const int ch = ((ks << 2) + lane4) ^ (row & 7);
        const bf16x8 bfr = *(const bf16x8*)&Bsm[(row << 6) + (ch << 3)];
#pragma unroll
        for (int mi = 0; mi < 4; ++mi)
          acc[mi][ni] = mfma16(af[mi], bfr, acc[mi][ni]);
      }
    }
    __syncthreads();
  }
}

// --------------- merged projections: qk (transposed out) + v, one dispatch
struct ProjAllArgs {
  const bf16_t* act[2];          // flT, rfT
  const float*  bias[2][2];      // [side][seg]: ql,kl / kr,qr
  float         scl[2][2];
  bf16_t*       outp[2][2];      // qlT,klT / krT,qrT
  const float*  vbias[2];        // vlb, vrb
  bf16_t*       vout[2];         // Vl, Vr
};
__global__ __launch_bounds__(256) void proj_all_kernel(const bf16_t* __restrict__ Wp, ProjAllArgs a)
{
  const int bid = blockIdx.x;
  const bool qk = bid < 512;
  int side, m0, n0;
  const bf16_t* Ap;
  const bf16_t* Bp;
  if (qk) {
    side = bid >> 8;
    const int rem = bid & 255;
    n0 = (rem & 15) << 7;          // activation rows
    m0 = (rem >> 4) << 7;          // stacked q/k rows
    Ap = a.act[side] + (size_t)n0 * 1024;
    Bp = Wp + (size_t)side * 2097152 + (size_t)m0 * 1024;
  } else {
    const int u = bid - 512;
    side = u >> 7;
    const int rem = u & 127;
    m0 = (rem & 7) << 7;           // v output rows
    n0 = (rem >> 3) << 7;          // activation rows
    Ap = Wp + 4194304ull + (size_t)side * 1048576 + (size_t)m0 * 1024;
    Bp = a.act[side] + (size_t)n0 * 1024;
  }

  const f32x4 fz = {0.f, 0.f, 0.f, 0.f};
  f32x4 acc[4][4];
#pragma unroll
  for (int i = 0; i < 4; ++i)
#pragma unroll
    for (int j = 0; j < 4; ++j) acc[i][j] = fz;
  gemm_accum(Ap, 1024, Bp, 1024, 1024, acc);

  const int lane = threadIdx.x & 63, wv = threadIdx.x >> 6;
  const int wm = wv >> 1, wn = wv & 1;
  const int lane15 = lane & 15, lane4 = lane >> 4;

  if (qk) {
    const int seg = m0 >> 10;
    const float* __restrict__ bias = a.bias[side][seg];
    const float bscale = a.scl[side][seg];
    bf16_t* __restrict__ C = a.outp[side][seg];
    const int mloc = (m0 & 1023) + (wn << 6);
    float bv[4];
#pragma unroll
    for (int ni = 0; ni < 4; ++ni) bv[ni] = bias[mloc + (ni << 4) + lane15] * bscale;
#pragma unroll
    for (int mi = 0; mi < 4; ++mi) {
      const int rowb = n0 + (wm << 6) + (mi << 4) + (lane4 << 2);
#pragma unroll
      for (int r = 0; r < 4; ++r) {
#pragma unroll
        for (int ni = 0; ni < 4; ++ni) {
          const int col = mloc + (ni << 4) + lane15;
          C[(size_t)(rowb + r) * 1024 + col] = (bf16_t)(acc[mi][ni][r] + bv[ni]);
        }
      }
    }
  } else {
    const float* __restrict__ bias = a.vbias[side];
    bf16_t* __restrict__ C = a.vout[side];
#pragma unroll
    for (int mi = 0; mi < 4; ++mi) {
      const int row0 = m0 + (wm << 6) + (mi << 4) + (lane4 << 2);
#pragma unroll
      for (int r = 0; r < 4; ++r) {
        const float bia = bias[row0 + r];
#pragma unroll
        for (int ni = 0; ni < 4; ++ni) {
          const int col = n0 + (wn << 6) + (ni << 4) + lane15;
          C[(size_t)(row0 + r) * 2048 + col] = (bf16_t)(acc[mi][ni][r] + bia);
        }
      }
    }
  }
}

// ------------------------------------------------- fused proj (split-K x2)
__global__ __launch_bounds__(256) void fused_gemm_kernel(
    const bf16_t* __restrict__ Wf, const bf16_t* __restrict__ Bt, bf16_t* __restrict__ Pf)
{
  const int z = blockIdx.z;
  const int m0 = blockIdx.x << 7;
  const int n0 = blockIdx.y << 7;
  const f32x4 fz = {0.f, 0.f, 0.f, 0.f};
  f32x4 acc[4][4];
#pragma unroll
  for (int i = 0; i < 4; ++i)
#pragma unroll
    for (int j = 0; j < 4; ++j) acc[i][j] = fz;
  gemm_accum(Wf + (size_t)m0 * 1024 + (z << 9), 1024,
             Bt + (size_t)n0 * 1024 + (z << 9), 1024, 512, acc);

  const int lane = threadIdx.x & 63, wv = threadIdx.x >> 6;
  const int wm = wv >> 1, wn = wv & 1;
  const int lane15 = lane & 15, lane4 = lane >> 4;
  bf16_t* __restrict__ C = Pf + ((size_t)z << 22);
#pragma unroll
  for (int mi = 0; mi < 4; ++mi) {
    const int row0 = m0 + (wm << 6) + (mi << 4) + (lane4 << 2);
#pragma unroll
    for (int r = 0; r < 4; ++r) {
#pragma unroll
      for (int ni = 0; ni < 4; ++ni) {
        const int col = n0 + (wn << 6) + (ni << 4) + lane15;
        C[(size_t)(row0 + r) * 4096 + col] = (bf16_t)acc[mi][ni][r];
      }
    }
  }
}

// ------------------------------------ GN (l/r) apply (mu/rstd from partials)
__global__ __launch_bounds__(256) void gn_apply_lr_kernel(
    const bf16_t* __restrict__ yl, const bf16_t* __restrict__ yr,
    const float* __restrict__ gl, const float* __restrict__ bl,
    const float* __restrict__ gr, const float* __restrict__ br,
    const float* __restrict__ pS_lr, const float* __restrict__ pQ_lr,
    bf16_t* __restrict__ flT, bf16_t* __restrict__ rfT)
{
  const int side = blockIdx.z;
  const int n0 = blockIdx.x << 6;
  const int c0 = blockIdx.y << 6;
  const bf16_t* __restrict__ y = side ? yr : yl;
  const float* __restrict__ gamma = side ? gr : gl;
  const float* __restrict__ beta  = side ? br : bl;
  __shared__ float L[64][65];
  const int tid = threadIdx.x;
#pragma unroll
  for (int j = 0; j < 2; ++j) {
    const int u = tid + (j << 8);
    const int cr = u >> 3, ch = u & 7;
    const bf16x8 v = *(const bf16x8*)&y[(size_t)(c0 + cr) * 2048 + n0 + (ch << 3)];
#pragma unroll
    for (int e = 0; e < 8; ++e) L[cr][(ch << 3) + e] = (float)v[e];
  }
  __syncthreads();
  const int b = n0 >> 10;
  bf16_t* __restrict__ outT = side ? rfT : flT;
#pragma unroll
  for (int j = 0; j < 2; ++j) {
    const int u = tid + (j << 8);
    const int nr = u >> 3, c8 = u & 7;
    const int n = n0 + nr;
    const int nf = side ? ((n & ~7) | (7 - (n & 7))) : n;
    const int cbase = c0 + (c8 << 3);
    const int gidx = (side << 6) + (b << 5) + (cbase >> 5);
    const float m = pS_lr[gidx] * (1.f / 32768.f);
    const float rs = rsqrtf(pQ_lr[gidx] * (1.f / 32768.f) - m * m + 1e-5f);
    bf16x8 v;
#pragma unroll
    for (int e = 0; e < 8; ++e) {
      const int c = cbase + e;
      const float xv = (L[(c8 << 3) + e][nr] - m) * rs * gamma[c] + beta[c];
      v[e] = (bf16_t)fmaxf(xv, 0.f);
    }
    *(bf16x8*)&outT[(size_t)nf * 1024 + cbase] = v;
  }
}

// --------------------------------------------------------------- attention
#define ATTN_STAGE(IT, BUF)                                                   \
  _Pragma("unroll")                                                           \
  for (int j_ = 0; j_ < 4; ++j_) {                                            \
    const int g_ = (wv << 2) + j_;                                            \
    const int row_ = (g_ << 2) + lane4;                                       \
    gload_lds16(kt + (size_t)((b << 10) + ((IT) << 6) + row_) * 1024 + (h << 7) + ((lane15 ^ (row_ & 7)) << 3), \
                &Ks[BUF][g_ << 9]);                                           \
  }                                                                           \
  _Pragma("unroll")                                                           \
  for (int j_ = 0; j_ < 4; ++j_) {                                            \
    const int g_ = (wv << 2) + j_;                                            \
    const int row_ = (g_ << 3) + (lane >> 3);                                 \
    gload_lds16(vm + (size_t)((h << 7) + row_) * 2048 + (b << 10) + ((IT) << 6) + (((lane & 7) ^ (row_ & 7)) << 3), \
                &Vs[BUF][g_ << 9]);                                           \
  }

__global__ __launch_bounds__(256, 2) void attn_kernel(
    const bf16_t* __restrict__ qlt, const bf16_t* __restrict__ krt, const bf16_t* __restrict__ vrm,
    const bf16_t* __restrict__ qrt, const bf16_t* __restrict__ klt, const bf16_t* __restrict__ vlm,
    bf16_t* __restrict__ xfc)
{
  const int st = blockIdx.x;
  const int bh = blockIdx.y;
  const int az = blockIdx.z;
  const int b = bh >> 3, h = bh & 7;
  const bf16_t* __restrict__ qt = az ? qrt : qlt;
  const bf16_t* __restrict__ kt = az ? klt : krt;
  const bf16_t* __restrict__ vm = az ? vlm : vrm;

  __shared__ bf16_t Ks[2][64 * 128];
  __shared__ bf16_t Vs[2][128 * 64];
  __shared__ bf16_t Ps[4][16 * 64];

  const int tid = threadIdx.x, lane = tid & 63, wv = tid >> 6;
  const int lane15 = lane & 15, lane4 = lane >> 4;

  bf16x8 qf[4];
  {
    const bf16_t* __restrict__ qbase = qt + (size_t)((b << 10) + (st << 6)) * 1024 + (h << 7);
    const int row = (wv << 4) + lane15;
#pragma unroll
    for (int kk = 0; kk < 4; ++kk)
      qf[kk] = *(const bf16x8*)&qbase[(size_t)row * 1024 + (kk << 5) + (lane4 << 3)];
  }

  const f32x4 fz = {0.f, 0.f, 0.f, 0.f};
  f32x4 oacc[8];
#pragma unroll
  for (int nj = 0; nj < 8; ++nj) oacc[nj] = fz;
  float mrun[4], lrun[4];
#pragma unroll
  for (int r = 0; r < 4; ++r) { mrun[r] = -3.0e38f; lrun[r] = 0.f; }

  ATTN_STAGE(0, 0)
  ATTN_STAGE(1, 1)

  for (int it = 0; it < 16; ++it) {
    const int cur = it & 1;
    if (it < 15) { asm volatile("s_waitcnt vmcnt(8)" ::: "memory"); }
    else         { asm volatile("s_waitcnt vmcnt(0)" ::: "memory"); }
    __builtin_amdgcn_s_barrier();
    f32x4 la[4];
#pragma unroll
    for (int tj = 0; tj < 4; ++tj) la[tj] = fz;
#pragma unroll
    for (int kk = 0; kk < 4; ++kk) {
#pragma unroll
      for (int tj = 0; tj < 4; ++tj) {
        const int row = (tj << 4) + lane15;
        const int ch = ((kk << 2) + lane4) ^ (row & 7);
        const bf16x8 kf = *(const bf16x8*)&Ks[cur][(row << 7) + (ch << 3)];
        la[tj] = mfma16(qf[kk], kf, la[tj]);
      }
    }
    float mx[4];
    int ok = 1;
#pragma unroll
    for (int r = 0; r < 4; ++r) {
      float m_ = la[0][r];
#pragma unroll
      for (int tj = 1; tj < 4; ++tj) m_ = fmaxf(m_, la[tj][r]);
#pragma unroll
      for (int o = 1; o < 16; o <<= 1) m_ = fmaxf(m_, __shfl_xor(m_, o, 64));
      mx[r] = m_;
      ok &= (m_ <= mrun[r] + 8.f) ? 1 : 0;
    }
    if (!__all(ok)) {
#pragma unroll
      for (int r = 0; r < 4; ++r) {
        const float mnew = fmaxf(mrun[r], mx[r]);
        const float alpha = __builtin_amdgcn_exp2f(mrun[r] - mnew);
        mrun[r] = mnew;
        lrun[r] *= alpha;
#pragma unroll
        for (int nj = 0; nj < 8; ++nj) oacc[nj][r] *= alpha;
      }
    }
#pragma unroll
    for (int r = 0; r < 4; ++r) {
      const int row = (lane4 << 2) + r;
      float rs = 0.f;
#pragma unroll
      for (int tj = 0; tj < 4; ++tj) {
        const float p = __builtin_amdgcn_exp2f(la[tj][r] - mrun[r]);
        rs += p;
        const int byte_ = ((tj << 5) + (lane15 << 1)) ^ ((row & 7) << 4);
        *(bf16_t*)((char*)(&Ps[wv][0]) + (row << 7) + byte_) = (bf16_t)p;
      }
#pragma unroll
      for (int o = 1; o < 16; o <<= 1) rs += __shfl_xor(rs, o, 64);
      lrun[r] += rs;
    }
#pragma unroll
    for (int kk = 0; kk < 2; ++kk) {
      const int prow = lane15;
      const int pch = ((kk << 2) + lane4) ^ (prow & 7);
      const bf16x8 pf = *(const bf16x8*)&Ps[wv][(prow << 6) + (pch << 3)];
#pragma unroll
      for (int nj = 0; nj < 8; ++nj) {
        const int row = (nj << 4) + lane15;
        const int ch = ((kk << 2) + lane4) ^ (row & 7);
        const bf16x8 vf = *(const bf16x8*)&Vs[cur][(row << 6) + (ch << 3)];
        oacc[nj] = mfma16(pf, vf, oacc[nj]);
      }
    }
    __builtin_amdgcn_s_barrier();
    if (it + 2 < 16) { ATTN_STAGE(it + 2, cur) }
  }
#pragma unroll
  for (int r = 0; r < 4; ++r) {
    const int sl = (wv << 4) + (lane4 << 2) + r;
    const int s = (st << 6) + sl;
    const int dd = s >> 7, hh2 = (s >> 3) & 15, ww = s & 7;
    const int w16 = az ? (15 - ww) : ww;
    const int n16 = (b << 11) + ((dd << 4) + hh2) * 16 + w16;
    const float inv = 1.f / lrun[r];
#pragma unroll
    for (int nj = 0; nj < 8; ++nj) {
      const int c = (h << 7) + (nj << 4) + lane15;
      xfc[(size_t)n16 * 1024 + c] = (bf16_t)(oacc[nj][r] * inv);
    }
  }
}

// -------------------------------------------------------------- GN (fused)
__global__ __launch_bounds__(256) void gn_partial_f_kernel(
    const bf16_t* __restrict__ Pf, const float* __restrict__ bias,
    float* __restrict__ pS, float* __restrict__ pQ)
{
  const int bg = blockIdx.x;
  const int sl = blockIdx.y;
  const int b = bg >> 5, g = bg & 31;
  const int tid = threadIdx.x;
  const int c = (g << 5) + (tid >> 3);
  const int s0 = (sl << 8) + ((tid & 7) << 5);
  const size_t base = (size_t)c * 4096 + (b << 11) + s0;
  const float bia = bias[c];
  float s = 0.f, q = 0.f;
#pragma unroll
  for (int u = 0; u < 4; ++u) {
    const bf16x8 v0 = *(const bf16x8*)&Pf[base + (u << 3)];
    const bf16x8 v1 = *(const bf16x8*)&Pf[base + (u << 3) + 4194304];
#pragma unroll
    for (int e = 0; e < 8; ++e) {
      const float v = (float)v0[e] + (float)v1[e] + bia;
      s += v; q += v * v;
    }
  }
  __shared__ float sb[8];
  const int lane = tid & 63, wv = tid >> 6;
#pragma unroll
  for (int o = 1; o < 64; o <<= 1) { s += __shfl_xor(s, o, 64); q += __shfl_xor(q, o, 64); }
  if (lane == 0) { sb[wv] = s; sb[4 + wv] = q; }
  __syncthreads();
  if (tid == 0) {
    pS[(bg << 3) + sl] = sb[0] + sb[1] + sb[2] + sb[3];
    pQ[(bg << 3) + sl] = sb[4] + sb[5] + sb[6] + sb[7];
  }
}

__global__ __launch_bounds__(256) void gn_apply_f_kernel(
    const bf16_t* __restrict__ Pf, const float* __restrict__ bias,
    const float* __restrict__ gamma, const float* __restrict__ beta,
    const float* __restrict__ pS, const float* __restrict__ pQ,
    float* __restrict__ outp)
{
  const int id = blockIdx.x * 256 + threadIdx.x;
  const int s8 = id & 255;
  const int c = (id >> 8) & 1023;
  const int b = id >> 18;
  const int gidx = (b << 5) + (c >> 5);
  float S = 0.f, Q = 0.f;
#pragma unroll
  for (int sl = 0; sl < 8; ++sl) { S += pS[(gidx << 3) + sl]; Q += pQ[(gidx << 3) + sl]; }
  const float m = S * (1.f / 65536.f);
  const float rs = rsqrtf(Q * (1.f / 65536.f) - m * m + 1e-5f);
  const float gm = gamma[c], bt = beta[c], bia = bias[c];
  const size_t idx = (size_t)c * 4096 + (b << 11) + (s8 << 3);
  const bf16x8 v0 = *(const bf16x8*)&Pf[idx];
  const bf16x8 v1 = *(const bf16x8*)&Pf[idx + 4194304];
  float o[8];
#pragma unroll
  for (int e = 0; e < 8; ++e) {
    const float v = (float)v0[e] + (float)v1[e] + bia;
    o[e] = fmaxf((v - m) * rs * gm + bt, 0.f);
  }
  float* __restrict__ op = &outp[(((size_t)(b << 10) + c) << 11) + (s8 << 3)];
  float4 o0, o1;
  o0.x = o[0]; o0.y = o[1]; o0.z = o[2]; o0.w = o[3];
  o1.x = o[4]; o1.y = o[5]; o1.z = o[6]; o1.w = o[7];
  *(float4*)op = o0;
  *(float4*)(op + 4) = o1;
}

// ------------------------------------------------------------------- asym
__global__ __launch_bounds__(256) void asym_kernel(
    const bf16_t* __restrict__ flT, const bf16_t* __restrict__ rfT, float* __restrict__ outp)
{
  const int n = blockIdx.x;
  const int tid = threadIdx.x;
  const bf16x4 a = *(const bf16x4*)&flT[(size_t)n * 1024 + (tid << 2)];
  const bf16x4 c = *(const bf16x4*)&rfT[(size_t)n * 1024 + (tid << 2)];
  float s = 0.f;
#pragma unroll
  for (int e = 0; e < 4; ++e) s += fabsf((float)a[e] - (float)c[e]);
  __shared__ float sb[4];
  const int lane = tid & 63, wv = tid >> 6;
#pragma unroll
  for (int o = 1; o < 64; o <<= 1) s += __shfl_xor(s, o, 64);
  if (lane == 0) sb[wv] = s;
  __syncthreads();
  if (tid == 0) outp[n] = (sb[0] + sb[1] + sb[2] + sb[3]) * (1.f / 1024.f);
}

// ================================================================== launch
extern "C" void kernel_launch(void* const* d_in, const int* in_sizes, int n_in,
                              void* d_out, int out_size, void* d_ws, size_t ws_size,
                              hipStream_t stream)
{
  (void)in_sizes; (void)n_in; (void)out_size; (void)ws_size;
  const float* x    = (const float*)d_in[0];
  const float* clw  = (const float*)d_in[1];
  const float* clb  = (const float*)d_in[2];
  const float* glg  = (const float*)d_in[3];
  const float* glb_ = (const float*)d_in[4];
  const float* crw  = (const float*)d_in[5];
  const float* crb  = (const float*)d_in[6];
  const float* grg  = (const float*)d_in[7];
  const float* grb  = (const float*)d_in[8];
  const float* qlw = (const float*)d_in[9];  const float* qlb = (const float*)d_in[10];
  const float* krw = (const float*)d_in[11]; const float* krb = (const float*)d_in[12];
  const float* vrw = (const float*)d_in[13]; const float* vrb = (const float*)d_in[14];
  const float* qrw = (const float*)d_in[15]; const float* qrb = (const float*)d_in[16];
  const float* klw = (const float*)d_in[17]; const float* klb = (const float*)d_in[18];
  const float* vlw = (const float*)d_in[19]; const float* vlb = (const float*)d_in[20];
  const float* fuw = (const float*)d_in[21]; const float* fub = (const float*)d_in[22];
  const float* gfg = (const float*)d_in[23]; const float* gfb = (const float*)d_in[24];
  float* out = (float*)d_out;

  char* ws = (char*)d_ws;
  size_t off = 0;
  auto take = [&](size_t bytes) -> char* {
    char* p = ws + off; off += (bytes + 255) & ~(size_t)255; return p;
  };
  bf16_t* Wb    = (bf16_t*)take(113246208ull);   // 2 x [1024][27648] bf16
  bf16_t* Wp    = (bf16_t*)take(14680064ull);    // 7 x [1024][1024] bf16 (stacked)
  bf16_t* Xp    = (bf16_t*)take(14745600ull);    // padded input bf16
  float*  pS_lr = (float*) take(512);            // contiguous with Xp: one memset
  float*  pQ_lr = (float*) take(512);
  bf16_t* convL = (bf16_t*)take(4194304ull);     // [1024][2048] bf16
  bf16_t* convR = (bf16_t*)take(4194304ull);
  bf16_t* flT   = (bf16_t*)take(4194304ull);     // [2048][1024]
  bf16_t* rfT   = (bf16_t*)take(4194304ull);
  float*  pS    = (float*) take(2048);
  float*  pQ    = (float*) take(2048);
  bf16_t* Pb    = (bf16_t*)take(33554432ull);    // 4 x 2 x [1024][2048] bf16 partials

  char* al = (char*)Wb; size_t aoff = 0;
  auto takeA = [&](size_t bytes) -> char* {
    char* p = al + aoff; aoff += (bytes + 255) & ~(size_t)255; return p;
  };
  bf16_t* qlT = (bf16_t*)takeA(4194304ull);      // [2048][1024]
  bf16_t* klT = (bf16_t*)takeA(4194304ull);
  bf16_t* krT = (bf16_t*)takeA(4194304ull);
  bf16_t* qrT = (bf16_t*)takeA(4194304ull);
  bf16_t* Vl  = (bf16_t*)takeA(4194304ull);      // [1024][2048]
  bf16_t* Vr  = (bf16_t*)takeA(4194304ull);
  bf16_t* xfcT = (bf16_t*)takeA(8388608ull);     // [4096][1024]
  bf16_t* Pf   = (bf16_t*)takeA(16777216ull);    // 2 x [1024][4096] bf16 split-K partials

  const float QS = 0.08838834764831843f * 1.4426950408889634f;  // SCALE * log2(e)

  hipMemsetAsync(Xp, 0, 14745600ull + 1024ull, stream);
  convw_kernel<<<dim3(4, 1024, 2), 256, 0, stream>>>(clw, crw, Wb);
  projw_kernel<<<dim3(1024, 7), 256, 0, stream>>>(qlw, klw, krw, qrw, vlw, vrw, fuw, Wp, QS);
  xp_build_kernel<<<dim3(16, 8, 4), 256, 0, stream>>>(x, Xp);
  conv8_kernel<<<dim3(256), 512, 0, stream>>>(Wb, Xp, Pb);
  reduce4_kernel<<<dim3(2048), 256, 0, stream>>>(Pb, clb, crb, convL, convR, pS_lr, pQ_lr);
  gn_apply_lr_kernel<<<dim3(32, 16, 2), 256, 0, stream>>>(convL, convR, glg, glb_, grg, grb,
                                                          pS_lr, pQ_lr, flT, rfT);
  ProjAllArgs pa;
  pa.act[0] = flT; pa.act[1] = rfT;
  pa.bias[0][0] = qlb; pa.bias[0][1] = klb;
  pa.bias[1][0] = krb; pa.bias[1][1] = qrb;
  pa.scl[0][0] = QS;  pa.scl[0][1] = 1.f;
  pa.scl[1][0] = 1.f; pa.scl[1][1] = QS;
  pa.outp[0][0] = qlT; pa.outp[0][1] = klT;
  pa.outp[1][0] = krT; pa.outp[1][1] = qrT;
  pa.vbias[0] = vlb; pa.vbias[1] = vrb;
  pa.vout[0] = Vl;   pa.vout[1] = Vr;
  proj_all_kernel<<<dim3(768), 256, 0, stream>>>(Wp, pa);

  attn_kernel<<<dim3(16, 16, 2), 256, 0, stream>>>(qlT, krT, Vr, qrT, klT, Vl, xfcT);
  fused_gemm_kernel<<<dim3(8, 32, 2), 256, 0, stream>>>(Wp + 6ull * 1048576, xfcT, Pf);
  gn_partial_f_kernel<<<dim3(64, 8), 256, 0, stream>>>(Pf, fub, pS, pQ);
  gn_apply_f_kernel<<<dim3(2048), 256, 0, stream>>>(Pf, fub, gfg, gfb, pS, pQ, out);
  asym_kernel<<<dim3(2048), 256, 0, stream>>>(flT, rfT, out + 4194304);
}